// Round 3
// baseline (414.611 us; speedup 1.0000x reference)
//
#include <hip/hip_runtime.h>

// ---------------------------------------------------------------------------
// LinearAttention (FAVOR-style), all GEMMs as bf16 MFMA 16x16x32:
//   cvtx:  x fp32 -> xb[b][l][d] bf16 + xT[b][d][l] bf16 (register transpose,
//          no LDS, full-cacheline writes)
//   cvtw:  qw,kw fp32 -> wt[n][k] bf16 (n in [0,512): q cols then k cols)
//   proj:  128x256 tile, BK=64, global_load_lds(16B) + XOR-swizzled LDS.
//          block x=0 -> exp -> qp[m][e]; x=1 -> exp -> kT[b][e][l]
//   zinv:  1/(rowsum(qp)+1e-8)
//   kv:    kT @ xT^T, 4 K-splits, fp32 partials -> kvreduce -> kvT[b][d][e]
//   out:   (qp @ kv) * zinv, 128x256 tile
// ---------------------------------------------------------------------------

#define EMBED 1024
#define PROJ  256
#define LSEQ  4096
#define BATCH 8

typedef short  bfrag __attribute__((ext_vector_type(8)));
typedef float  f4    __attribute__((ext_vector_type(4)));
typedef unsigned short u16x8 __attribute__((ext_vector_type(8)));
typedef unsigned short u16x4 __attribute__((ext_vector_type(4)));

static __device__ __forceinline__ unsigned short f2bf(float f) {
  unsigned int u = __builtin_bit_cast(unsigned int, f);
  u += 0x7fffu + ((u >> 16) & 1u);  // RNE
  return (unsigned short)(u >> 16);
}
static __device__ __forceinline__ float bf2f(unsigned short h) {
  unsigned int u = ((unsigned int)h) << 16;
  return __builtin_bit_cast(float, u);
}

static __device__ __forceinline__ void gload_lds16(const void* g, void* l) {
  __builtin_amdgcn_global_load_lds(
      (__attribute__((address_space(1))) void*)(unsigned long long)(g),
      (__attribute__((address_space(3))) void*)(unsigned)(unsigned long long)(l),
      16, 0, 0);
}

// Stage a ROWSx64 bf16 tile via global_load_lds. Row-major rows of 8 16B
// chunks; chunk c stored at position c ^ (r&7) (conflict-free b128 frag reads,
// lane-sequential LDS dests).
template <int ROWS>
static __device__ __forceinline__ void stage_tile(
    const unsigned short* __restrict__ src, int row0, int stride, int k0,
    unsigned short* lds, int wave, int lane) {
  constexpr int G = ROWS / 32;
#pragma unroll
  for (int j = 0; j < G; j++) {
    int slot = (wave * G + j) * 64 + lane;
    int r = slot >> 3, cp = slot & 7;
    int c = cp ^ (r & 7);
    gload_lds16(src + (size_t)(row0 + r) * stride + k0 + c * 8,
                lds + (wave * G + j) * 512);
  }
}

static __device__ __forceinline__ bfrag read_frag(const unsigned short* lds,
                                                  int row, int chunk) {
  return *(const bfrag*)(lds + ((row << 3) + (chunk ^ (row & 7))) * 8);
}

// ---------------------------------------------------------------------------
// cvtx: register-transpose, no LDS. Tile 128(l) x 64(d) per block.
// Thread: dc = tid&15 (4 d's), lg = tid>>4 (8 consecutive l's).
// ---------------------------------------------------------------------------
__global__ __launch_bounds__(256) void cvtx_kernel(
    const float* __restrict__ x, unsigned short* __restrict__ xb,
    unsigned short* __restrict__ xT) {
  const int tid = threadIdx.x;
  const int dc = tid & 15, lg = tid >> 4;
  const int d0 = blockIdx.x * 64, l0 = blockIdx.y * 128, b = blockIdx.z;
  const int l = l0 + lg * 8;
  const int d = d0 + dc * 4;
  unsigned short h[8][4];
#pragma unroll
  for (int j = 0; j < 8; j++) {
    f4 v = *(const f4*)(x + ((size_t)(b * LSEQ + l + j)) * EMBED + d);
    u16x4 hv = (u16x4){f2bf(v[0]), f2bf(v[1]), f2bf(v[2]), f2bf(v[3])};
    *(u16x4*)(xb + ((size_t)(b * LSEQ + l + j)) * EMBED + d) = hv;
    h[j][0] = hv[0]; h[j][1] = hv[1]; h[j][2] = hv[2]; h[j][3] = hv[3];
  }
#pragma unroll
  for (int dd = 0; dd < 4; dd++) {
    u16x8 t;
#pragma unroll
    for (int j = 0; j < 8; j++) t[j] = h[j][dd];
    *(u16x8*)(xT + ((size_t)(b * EMBED + d + dd)) * LSEQ + l) = t;
  }
}

// ---------------------------------------------------------------------------
// cvtw: qw/kw fp32 [k][n] -> wt bf16 [n][k]  (1 MB total, not hot)
// ---------------------------------------------------------------------------
__global__ __launch_bounds__(256) void cvtw_kernel(
    const float* __restrict__ qw, const float* __restrict__ kw,
    unsigned short* __restrict__ wt) {
  __shared__ unsigned short T[64][66];
  const int tid = threadIdx.x;
  const int n0 = blockIdx.x * 64, k0 = blockIdx.y * 64;
  const float* W = blockIdx.z ? kw : qw;
#pragma unroll
  for (int it = 0; it < 4; it++) {
    int slot = it * 256 + tid;
    int r = slot >> 4, c4 = slot & 15;
    f4 v = *(const f4*)(W + (size_t)(k0 + r) * PROJ + n0 + c4 * 4);
#pragma unroll
    for (int j = 0; j < 4; j++) T[c4 * 4 + j][r] = f2bf(v[j]);
  }
  __syncthreads();
#pragma unroll
  for (int it = 0; it < 2; it++) {
    int slot = it * 256 + tid;
    int n = slot >> 3, ch = slot & 7;
    *(u16x8*)(wt + ((size_t)(blockIdx.z * PROJ + n0 + n)) * EMBED + k0 + ch * 8) =
        *(const u16x8*)&T[n][ch * 8];
  }
}

// ---------------------------------------------------------------------------
// proj: C[m][n] = exp(xb @ wt^T). M=32768, N=512, K=1024.
// 128x256 tile, BK=64. blockIdx.x==0 -> q half; ==1 -> k half.
// ---------------------------------------------------------------------------
__global__ __launch_bounds__(256) void proj_kernel(
    const unsigned short* __restrict__ xb, const unsigned short* __restrict__ wt,
    unsigned short* __restrict__ qp, unsigned short* __restrict__ kT) {
  __shared__ union {
    struct { unsigned short A[128 * 64]; unsigned short B[256 * 64]; } t;
    unsigned short T[128 * 136];
  } sm;
  const int tid = threadIdx.x, wave = tid >> 6, lane = tid & 63;
  const int quad = lane >> 4, l16 = lane & 15;
  const int wm = wave >> 1, wn = wave & 1;
  const int n0 = blockIdx.x * 256, m0 = blockIdx.y * 128;

  f4 acc[4][8];
#pragma unroll
  for (int i = 0; i < 4; i++)
#pragma unroll
    for (int j = 0; j < 8; j++) acc[i][j] = (f4){0.f, 0.f, 0.f, 0.f};

  for (int k0 = 0; k0 < EMBED; k0 += 64) {
    stage_tile<128>(xb, m0, EMBED, k0, sm.t.A, wave, lane);
    stage_tile<256>(wt, n0, EMBED, k0, sm.t.B, wave, lane);
    __syncthreads();
#pragma unroll
    for (int ks = 0; ks < 2; ks++) {
      bfrag a[4], bfr[8];
#pragma unroll
      for (int mt = 0; mt < 4; mt++)
        a[mt] = read_frag(sm.t.A, wm * 64 + mt * 16 + l16, ks * 4 + quad);
#pragma unroll
      for (int nt = 0; nt < 8; nt++)
        bfr[nt] = read_frag(sm.t.B, wn * 128 + nt * 16 + l16, ks * 4 + quad);
#pragma unroll
      for (int mt = 0; mt < 4; mt++)
#pragma unroll
        for (int nt = 0; nt < 8; nt++)
          acc[mt][nt] = __builtin_amdgcn_mfma_f32_16x16x32_bf16(
              a[mt], bfr[nt], acc[mt][nt], 0, 0, 0);
    }
    __syncthreads();
  }

  if (n0 == 0) {
    // q half: two passes of 128 cols through T[l][e_local]
#pragma unroll
    for (int h = 0; h < 2; h++) {
      __syncthreads();
      if (wn == h) {
#pragma unroll
        for (int mt = 0; mt < 4; mt++)
#pragma unroll
          for (int nt = 0; nt < 8; nt++)
#pragma unroll
            for (int r = 0; r < 4; r++)
              sm.T[(wm * 64 + mt * 16 + quad * 4 + r) * 136 + nt * 16 + l16] =
                  f2bf(__expf(acc[mt][nt][r]));
      }
      __syncthreads();
#pragma unroll
      for (int it = 0; it < 8; it++) {
        int slot = it * 256 + tid;
        int row = slot >> 4, ch = slot & 15;
        *(u16x8*)(qp + (size_t)(m0 + row) * PROJ + h * 128 + ch * 8) =
            *(const u16x8*)&sm.T[row * 136 + ch * 8];
      }
    }
  } else {
    // k half: two passes of 128 e-rows through T[e_local][l]
    const int bb = m0 >> 12, ll0 = m0 & 4095;
#pragma unroll
    for (int h = 0; h < 2; h++) {
      __syncthreads();
      if (wn == h) {
#pragma unroll
        for (int mt = 0; mt < 4; mt++)
#pragma unroll
          for (int nt = 0; nt < 8; nt++) {
            u16x4 hv;
#pragma unroll
            for (int r = 0; r < 4; r++) hv[r] = f2bf(__expf(acc[mt][nt][r]));
            *(u16x4*)&sm.T[(nt * 16 + l16) * 136 + wm * 64 + mt * 16 + quad * 4] = hv;
          }
      }
      __syncthreads();
#pragma unroll
      for (int it = 0; it < 8; it++) {
        int slot = it * 256 + tid;
        int e = slot >> 4, ch = slot & 15;
        *(u16x8*)(kT + (size_t)(bb * PROJ + h * 128 + e) * LSEQ + ll0 + ch * 8) =
            *(const u16x8*)&sm.T[e * 136 + ch * 8];
      }
    }
  }
}

// ---------------------------------------------------------------------------
// zinv[m] = 1 / (sum_e qp[m][e] + 1e-8)
// ---------------------------------------------------------------------------
__global__ __launch_bounds__(256) void zinv_kernel(
    const unsigned short* __restrict__ qp, float* __restrict__ zinv) {
  int m = blockIdx.x * 4 + (threadIdx.x >> 6);
  int lane = threadIdx.x & 63;
  u16x4 h = *(const u16x4*)(qp + (size_t)m * PROJ + lane * 4);
  float s = bf2f(h[0]) + bf2f(h[1]) + bf2f(h[2]) + bf2f(h[3]);
#pragma unroll
  for (int off = 32; off; off >>= 1) s += __shfl_xor(s, off);
  if (lane == 0) zinv[m] = 1.0f / (s + 1e-8f);
}

// ---------------------------------------------------------------------------
// kv: kvp[split][b][e][d] = sum_{l in 1024-chunk} kT[b][e][l] * xT[b][d][l]
// 128x128 tile, BK=64, 4 K-splits. grid (8 d, 2 e, 4*8)
// ---------------------------------------------------------------------------
__global__ __launch_bounds__(256) void kv_kernel(
    const unsigned short* __restrict__ kT, const unsigned short* __restrict__ xT,
    float* __restrict__ kvp) {
  __shared__ struct { unsigned short A[128 * 64]; unsigned short B[128 * 64]; } sm;
  const int tid = threadIdx.x, wave = tid >> 6, lane = tid & 63;
  const int quad = lane >> 4, l16 = lane & 15;
  const int wm = wave >> 1, wn = wave & 1;
  const int d0 = blockIdx.x * 128, e0 = blockIdx.y * 128;
  const int b = blockIdx.z & 7, split = blockIdx.z >> 3;
  const unsigned short* As = kT + (size_t)b * PROJ * LSEQ;
  const unsigned short* Bs = xT + (size_t)b * EMBED * LSEQ;

  f4 acc[4][4];
#pragma unroll
  for (int i = 0; i < 4; i++)
#pragma unroll
    for (int j = 0; j < 4; j++) acc[i][j] = (f4){0.f, 0.f, 0.f, 0.f};

  const int kbase = split * 1024;
  for (int kk = 0; kk < 1024; kk += 64) {
    stage_tile<128>(As, e0, LSEQ, kbase + kk, sm.A, wave, lane);
    stage_tile<128>(Bs, d0, LSEQ, kbase + kk, sm.B, wave, lane);
    __syncthreads();
#pragma unroll
    for (int ks = 0; ks < 2; ks++) {
      bfrag a[4], bfr[4];
#pragma unroll
      for (int mt = 0; mt < 4; mt++)
        a[mt] = read_frag(sm.A, wm * 64 + mt * 16 + l16, ks * 4 + quad);
#pragma unroll
      for (int nt = 0; nt < 4; nt++)
        bfr[nt] = read_frag(sm.B, wn * 64 + nt * 16 + l16, ks * 4 + quad);
#pragma unroll
      for (int mt = 0; mt < 4; mt++)
#pragma unroll
        for (int nt = 0; nt < 4; nt++)
          acc[mt][nt] = __builtin_amdgcn_mfma_f32_16x16x32_bf16(
              a[mt], bfr[nt], acc[mt][nt], 0, 0, 0);
    }
    __syncthreads();
  }

#pragma unroll
  for (int mt = 0; mt < 4; mt++)
#pragma unroll
    for (int nt = 0; nt < 4; nt++)
#pragma unroll
      for (int r = 0; r < 4; r++) {
        int e = e0 + wm * 64 + mt * 16 + quad * 4 + r;
        int d = d0 + wn * 64 + nt * 16 + l16;
        kvp[((size_t)(split * 8 + b) * PROJ + e) * EMBED + d] = acc[mt][nt][r];
      }
}

// ---------------------------------------------------------------------------
// kvreduce: kvT[b][d][e] bf16 = f2bf( sum_{4 splits} kvp[split][b][e][d] )
// ---------------------------------------------------------------------------
__global__ __launch_bounds__(256) void kvreduce_kernel(
    const float* __restrict__ kvp, unsigned short* __restrict__ kvT) {
  __shared__ float T[64][66];
  const int tid = threadIdx.x;
  const int d0 = blockIdx.x * 64, e0 = blockIdx.y * 64, b = blockIdx.z;
#pragma unroll
  for (int it = 0; it < 4; it++) {
    int slot = it * 256 + tid;
    int e = slot >> 4, c4 = slot & 15;
    f4 s = (f4){0.f, 0.f, 0.f, 0.f};
#pragma unroll
    for (int sp = 0; sp < 4; sp++)
      s += *(const f4*)(kvp + ((size_t)(sp * 8 + b) * PROJ + e0 + e) * EMBED + d0 + c4 * 4);
#pragma unroll
    for (int j = 0; j < 4; j++) T[c4 * 4 + j][e] = s[j];
  }
  __syncthreads();
#pragma unroll
  for (int it = 0; it < 2; it++) {
    int slot = it * 256 + tid;
    int d = slot >> 3, ch = slot & 7;
    u16x8 h;
#pragma unroll
    for (int j = 0; j < 8; j++) h[j] = f2bf(T[d][ch * 8 + j]);
    *(u16x8*)(kvT + ((size_t)(b * EMBED + d0 + d)) * PROJ + e0 + ch * 8) = h;
  }
}

// ---------------------------------------------------------------------------
// out: out[b][l][d] = (qp @ kv) * zinv. A=qp[l][e], B=kvT[d][e].
// 128x256 tile, BK=64, K=256. grid (4 d, 32 l, 8 b)
// ---------------------------------------------------------------------------
__global__ __launch_bounds__(256) void out_kernel(
    const unsigned short* __restrict__ qp, const unsigned short* __restrict__ kvT,
    const float* __restrict__ zinv, float* __restrict__ out) {
  __shared__ struct { unsigned short A[128 * 64]; unsigned short B[256 * 64]; } sm;
  __shared__ float zv[128];
  const int tid = threadIdx.x, wave = tid >> 6, lane = tid & 63;
  const int quad = lane >> 4, l16 = lane & 15;
  const int wm = wave >> 1, wn = wave & 1;
  const int d0 = blockIdx.x * 256, l0 = blockIdx.y * 128, b = blockIdx.z;
  const unsigned short* As = qp + (size_t)b * LSEQ * PROJ;
  const unsigned short* Bs = kvT + (size_t)b * EMBED * PROJ;

  if (tid < 128) zv[tid] = zinv[b * LSEQ + l0 + tid];

  f4 acc[4][8];
#pragma unroll
  for (int i = 0; i < 4; i++)
#pragma unroll
    for (int j = 0; j < 8; j++) acc[i][j] = (f4){0.f, 0.f, 0.f, 0.f};

  for (int k0 = 0; k0 < PROJ; k0 += 64) {
    stage_tile<128>(As, l0, PROJ, k0, sm.A, wave, lane);
    stage_tile<256>(Bs, d0, PROJ, k0, sm.B, wave, lane);
    __syncthreads();
#pragma unroll
    for (int ks = 0; ks < 2; ks++) {
      bfrag a[4], bfr[8];
#pragma unroll
      for (int mt = 0; mt < 4; mt++)
        a[mt] = read_frag(sm.A, wm * 64 + mt * 16 + l16, ks * 4 + quad);
#pragma unroll
      for (int nt = 0; nt < 8; nt++)
        bfr[nt] = read_frag(sm.B, wn * 128 + nt * 16 + l16, ks * 4 + quad);
#pragma unroll
      for (int mt = 0; mt < 4; mt++)
#pragma unroll
        for (int nt = 0; nt < 8; nt++)
          acc[mt][nt] = __builtin_amdgcn_mfma_f32_16x16x32_bf16(
              a[mt], bfr[nt], acc[mt][nt], 0, 0, 0);
    }
    __syncthreads();
  }

#pragma unroll
  for (int mt = 0; mt < 4; mt++)
#pragma unroll
    for (int nt = 0; nt < 8; nt++)
#pragma unroll
      for (int r = 0; r < 4; r++) {
        int row = wm * 64 + mt * 16 + quad * 4 + r;
        int d = d0 + wn * 128 + nt * 16 + l16;
        out[((size_t)(b * LSEQ + l0 + row)) * EMBED + d] = acc[mt][nt][r] * zv[row];
      }
}

// ---------------------------------------------------------------------------
// Workspace layout (bytes):
//   xb   @ 0          67,108,864   (bf16 [b][l][d]) -- aliased by kvp later
//   xT   @ 67108864   67,108,864   (bf16 [b][d][l])
//   wt   @ 134217728   1,048,576   (bf16 [n][k], n=[q|k])
//   qp   @ 135266304  16,777,216   (bf16 [m][e])
//   kT   @ 152043520  16,777,216   (bf16 [b][e][l])
//   kvT  @ 168820736   4,194,304   (bf16 [b][d][e])
//   zinv @ 173015040     131,072
//   kvp = xb region (33,554,432 = 4 splits * 8 * 256 * 1024 * 4)  [xb dead]
// ---------------------------------------------------------------------------
extern "C" void kernel_launch(void* const* d_in, const int* in_sizes, int n_in,
                              void* d_out, int out_size, void* d_ws, size_t ws_size,
                              hipStream_t stream) {
  const float* x  = (const float*)d_in[0];
  const float* qw = (const float*)d_in[1];
  const float* kw = (const float*)d_in[2];
  float* out = (float*)d_out;

  char* ws = (char*)d_ws;
  unsigned short* xb   = (unsigned short*)(ws);
  unsigned short* xT   = (unsigned short*)(ws + 67108864);
  unsigned short* wt   = (unsigned short*)(ws + 134217728);
  unsigned short* qp   = (unsigned short*)(ws + 135266304);
  unsigned short* kT   = (unsigned short*)(ws + 152043520);
  unsigned short* kvT  = (unsigned short*)(ws + 168820736);
  float*          zinv = (float*)(ws + 173015040);
  float*          kvp  = (float*)(ws);  // aliases xb (dead after proj)

  cvtx_kernel<<<dim3(16, 32, 8), 256, 0, stream>>>(x, xb, xT);
  cvtw_kernel<<<dim3(4, 16, 2), 256, 0, stream>>>(qw, kw, wt);
  proj_kernel<<<dim3(2, 256), 256, 0, stream>>>(xb, wt, qp, kT);
  zinv_kernel<<<dim3(8192), 256, 0, stream>>>(qp, zinv);
  kv_kernel<<<dim3(8, 2, 32), 256, 0, stream>>>(kT, xT, kvp);
  kvreduce_kernel<<<dim3(16, 4, 8), 256, 0, stream>>>(kvp, kvT);
  out_kernel<<<dim3(4, 32, 8), 256, 0, stream>>>(qp, kvT, zinv, out);
}